// Round 1
// baseline (408.988 us; speedup 1.0000x reference)
//
#include <hip/hip_runtime.h>

#define HD  64
#define FIN 128

// ---- workspace float offsets ----
#define WS_W1T  0        // [128][64] transposed W1
#define WS_W2T  8192     // [64][64]  transposed W2
#define WS_WKT  12288
#define WS_WQT  16384
#define WS_WVT  20480
#define WS_WSK  24576    // wsk[64] = Ws^T @ Wsc
#define WS_BASE 24640    // scalar: bsc + b_gate . Wsc   (padded to 24704)
#define WS_H    24704    // h  [N][64]
// k, q, vw buffers follow, offsets computed at launch

// ---------------------------------------------------------------------------
// Prep: transpose weights into ws, fold scorer through skip path.
// ---------------------------------------------------------------------------
__global__ void gnn_prep(const float* __restrict__ W1, const float* __restrict__ W2,
                         const float* __restrict__ Wk, const float* __restrict__ Wq,
                         const float* __restrict__ Wv, const float* __restrict__ Wsm,
                         const float* __restrict__ Wsc, const float* __restrict__ bgate,
                         const float* __restrict__ bsc, float* __restrict__ ws) {
    int b = blockIdx.x, t = threadIdx.x;
    if (b == 0) {
        for (int idx = t; idx < HD * FIN; idx += blockDim.x) {
            int c = idx / FIN, j = idx % FIN;          // W1[c][j]
            ws[WS_W1T + j * HD + c] = W1[idx];
        }
    } else if (b <= 4) {
        const float* src = (b == 1) ? W2 : (b == 2) ? Wk : (b == 3) ? Wq : Wv;
        int off = (b == 1) ? WS_W2T : (b == 2) ? WS_WKT : (b == 3) ? WS_WQT : WS_WVT;
        for (int idx = t; idx < HD * HD; idx += blockDim.x) {
            int c = idx / HD, j = idx % HD;
            ws[off + j * HD + c] = src[idx];
        }
    } else {
        if (t < HD) {
            float acc = 0.f;
            for (int c = 0; c < HD; ++c) acc += Wsm[c * HD + t] * Wsc[c];
            ws[WS_WSK + t] = acc;
        }
        if (t == 0) {
            float acc = bsc[0];
            for (int c = 0; c < HD; ++c) acc += bgate[c] * Wsc[c];
            ws[WS_BASE] = acc;
        }
    }
}

// ---------------------------------------------------------------------------
// MLP: h = relu(x@W1^T + b1)@W2^T + b2.
// 16 lanes per node (4 features each), 4 nodes per wave, 16 nodes per block.
// Weights transposed in LDS -> ds_read_b128, broadcast x/h reads.
// LDS: 12288 (W1T+W2T) + 64 + 64 + 2112 (xs) + 1088 (h1s) = 15616 f = 62.5 KB
// ---------------------------------------------------------------------------
__global__ __launch_bounds__(256) void gnn_mlp(const float* __restrict__ x,
                                               const float* __restrict__ b1g,
                                               const float* __restrict__ b2g,
                                               const float* __restrict__ ws,
                                               float* __restrict__ hout, int N) {
    __shared__ float lds[15616];
    const int L_W1T = 0, L_W2T = 8192, L_B1 = 12288, L_B2 = 12352,
              L_XS = 12416, L_H1S = 14528;
    int tid = threadIdx.x;
    for (int i = tid * 4; i < 12288; i += 1024) {
        float4 v = *(const float4*)&ws[i];
        *(float4*)&lds[i] = v;
    }
    if (tid < HD) { lds[L_B1 + tid] = b1g[tid]; lds[L_B2 + tid] = b2g[tid]; }
    __syncthreads();

    int w = tid >> 6, l = tid & 63;
    int g = l >> 4, f = l & 15;
    const float* xrow  = &lds[L_XS  + w * 528 + g * 132];
    float*       h1row = &lds[L_H1S + w * 272 + g * 68];

    for (int nbase = blockIdx.x * 16; nbase < N; nbase += gridDim.x * 16) {
        // stage x rows for this wave's 4 nodes (coalesced float4)
        #pragma unroll
        for (int r = 0; r < 2; ++r) {
            int p = r * 64 + l;
            int gg = p >> 5, c4 = p & 31;
            int node = nbase + w * 4 + gg;
            float4 xv = make_float4(0.f, 0.f, 0.f, 0.f);
            if (node < N) xv = ((const float4*)x)[node * 32 + c4];
            *(float4*)&lds[L_XS + w * 528 + gg * 132 + c4 * 4] = xv;
        }
        // GEMM1: h1[4f..4f+3] = relu(b1 + x . W1T)
        float4 acc = *(const float4*)&lds[L_B1 + 4 * f];
        for (int j = 0; j < FIN; j += 4) {
            float4 xv = *(const float4*)&xrow[j];
            const float* xp = (const float*)&xv;
            #pragma unroll
            for (int jj = 0; jj < 4; ++jj) {
                float4 wv = *(const float4*)&lds[L_W1T + (j + jj) * HD + 4 * f];
                acc.x += xp[jj] * wv.x; acc.y += xp[jj] * wv.y;
                acc.z += xp[jj] * wv.z; acc.w += xp[jj] * wv.w;
            }
        }
        acc.x = fmaxf(acc.x, 0.f); acc.y = fmaxf(acc.y, 0.f);
        acc.z = fmaxf(acc.z, 0.f); acc.w = fmaxf(acc.w, 0.f);
        *(float4*)&h1row[4 * f] = acc;
        // GEMM2: h = b2 + h1 . W2T
        float4 a2 = *(const float4*)&lds[L_B2 + 4 * f];
        for (int j = 0; j < HD; j += 4) {
            float4 hv = *(const float4*)&h1row[j];
            const float* hp = (const float*)&hv;
            #pragma unroll
            for (int jj = 0; jj < 4; ++jj) {
                float4 wv = *(const float4*)&lds[L_W2T + (j + jj) * HD + 4 * f];
                a2.x += hp[jj] * wv.x; a2.y += hp[jj] * wv.y;
                a2.z += hp[jj] * wv.z; a2.w += hp[jj] * wv.w;
            }
        }
        int n = nbase + w * 4 + g;
        if (n < N) *(float4*)&hout[n * HD + 4 * f] = a2;
    }
}

// ---------------------------------------------------------------------------
// k/q/vw + score base: k = h@Wk^T+bk, q likewise, vw = (h@Wv^T+bv) . Wsc,
// score[n] = base_const + h . wsk
// LDS: 12288 + 64 (wsk) + 192 + 64 + 1088 = 13696 f = 54.8 KB
// ---------------------------------------------------------------------------
__global__ __launch_bounds__(256) void gnn_kqv(const float* __restrict__ ws,
                                               const float* __restrict__ bkg,
                                               const float* __restrict__ bqg,
                                               const float* __restrict__ bvg,
                                               const float* __restrict__ wscg,
                                               float* __restrict__ kout,
                                               float* __restrict__ qout,
                                               float* __restrict__ vwout,
                                               float* __restrict__ score, int N) {
    __shared__ float lds[13696];
    const int L_WKT = 0, L_WQT = 4096, L_WVT = 8192, L_WSK = 12288,
              L_BK = 12352, L_BQ = 12416, L_BV = 12480, L_WSC = 12544, L_HS = 12608;
    int tid = threadIdx.x;
    for (int i = tid * 4; i < 12352; i += 1024) {       // WkT,WqT,WvT,wsk
        float4 v = *(const float4*)&ws[WS_WKT + i];
        *(float4*)&lds[i] = v;
    }
    if (tid < HD) {
        lds[L_BK + tid] = bkg[tid]; lds[L_BQ + tid] = bqg[tid];
        lds[L_BV + tid] = bvg[tid]; lds[L_WSC + tid] = wscg[tid];
    }
    __syncthreads();
    float basec = ws[WS_BASE];
    const float* hbuf = ws + WS_H;

    int w = tid >> 6, l = tid & 63;
    int g = l >> 4, f = l & 15;
    const float* hrow = &lds[L_HS + w * 272 + g * 68];

    for (int nbase = blockIdx.x * 16; nbase < N; nbase += gridDim.x * 16) {
        // stage h rows: 4 nodes x 64 f = 64 float4 per wave, one round
        {
            int gg = l >> 4, c4 = l & 15;
            int node = nbase + w * 4 + gg;
            float4 hv = make_float4(0.f, 0.f, 0.f, 0.f);
            if (node < N) hv = ((const float4*)hbuf)[node * 16 + c4];
            *(float4*)&lds[L_HS + w * 272 + gg * 68 + c4 * 4] = hv;
        }
        float4 aK = *(const float4*)&lds[L_BK + 4 * f];
        float4 aQ = *(const float4*)&lds[L_BQ + 4 * f];
        float4 aV = *(const float4*)&lds[L_BV + 4 * f];
        float  aS = 0.f;
        for (int j = 0; j < HD; j += 4) {
            float4 hv = *(const float4*)&hrow[j];
            const float* hp = (const float*)&hv;
            float4 wk4 = *(const float4*)&lds[L_WSK + j];
            aS += hv.x * wk4.x + hv.y * wk4.y + hv.z * wk4.z + hv.w * wk4.w;
            #pragma unroll
            for (int jj = 0; jj < 4; ++jj) {
                float hj = hp[jj];
                float4 wk = *(const float4*)&lds[L_WKT + (j + jj) * HD + 4 * f];
                float4 wq = *(const float4*)&lds[L_WQT + (j + jj) * HD + 4 * f];
                float4 wv = *(const float4*)&lds[L_WVT + (j + jj) * HD + 4 * f];
                aK.x += hj * wk.x; aK.y += hj * wk.y; aK.z += hj * wk.z; aK.w += hj * wk.w;
                aQ.x += hj * wq.x; aQ.y += hj * wq.y; aQ.z += hj * wq.z; aQ.w += hj * wq.w;
                aV.x += hj * wv.x; aV.y += hj * wv.y; aV.z += hj * wv.z; aV.w += hj * wv.w;
            }
        }
        int n = nbase + w * 4 + g;
        if (n < N) {
            ((float4*)kout)[n * 16 + f] = aK;
            ((float4*)qout)[n * 16 + f] = aQ;
            float4 sc = *(const float4*)&lds[L_WSC + 4 * f];
            float4 vw = make_float4(aV.x * sc.x, aV.y * sc.y, aV.z * sc.z, aV.w * sc.w);
            ((float4*)vwout)[n * 16 + f] = vw;
            if (f == 0) score[n] = basec + aS;
        }
    }
}

// ---------------------------------------------------------------------------
// Edge: score[dst] += sum_t sigmoid(k[dst]+q[src])_t * vw[src]_t
// 16 lanes per edge, float4 gathers, shuffle reduce, ONE atomic per edge.
// ---------------------------------------------------------------------------
__global__ __launch_bounds__(256) void gnn_edge(const int* __restrict__ ei,
                                                const float* __restrict__ kb,
                                                const float* __restrict__ qb,
                                                const float* __restrict__ vb,
                                                float* __restrict__ score, int E) {
    int t = blockIdx.x * 256 + threadIdx.x;
    int e = t >> 4;
    if (e >= E) return;
    int f = t & 15;
    int s = ei[e];
    int d = ei[E + e];
    float4 kk = ((const float4*)kb)[d * 16 + f];
    float4 qq = ((const float4*)qb)[s * 16 + f];
    float4 vv = ((const float4*)vb)[s * 16 + f];
    float s0 = 1.f / (1.f + __expf(-(kk.x + qq.x)));
    float s1 = 1.f / (1.f + __expf(-(kk.y + qq.y)));
    float s2 = 1.f / (1.f + __expf(-(kk.z + qq.z)));
    float s3 = 1.f / (1.f + __expf(-(kk.w + qq.w)));
    float p = vv.x * s0 + vv.y * s1 + vv.z * s2 + vv.w * s3;
    p += __shfl_down(p, 8, 16);
    p += __shfl_down(p, 4, 16);
    p += __shfl_down(p, 2, 16);
    p += __shfl_down(p, 1, 16);
    if (f == 0) atomicAdd(&score[d], p);
}

// ---------------------------------------------------------------------------
extern "C" void kernel_launch(void* const* d_in, const int* in_sizes, int n_in,
                              void* d_out, int out_size, void* d_ws, size_t ws_size,
                              hipStream_t stream) {
    const float* x    = (const float*)d_in[0];
    const int*   ei   = (const int*)d_in[1];
    const float* W1   = (const float*)d_in[2];
    const float* b1   = (const float*)d_in[3];
    const float* W2   = (const float*)d_in[4];
    const float* b2   = (const float*)d_in[5];
    const float* Wk   = (const float*)d_in[6];
    const float* bk   = (const float*)d_in[7];
    const float* Wq   = (const float*)d_in[8];
    const float* bq   = (const float*)d_in[9];
    const float* Wv   = (const float*)d_in[10];
    const float* bv   = (const float*)d_in[11];
    const float* Wsm  = (const float*)d_in[12];
    const float* bgat = (const float*)d_in[13];
    const float* Wsc  = (const float*)d_in[14];
    const float* bsc  = (const float*)d_in[15];

    int N = in_sizes[0] / FIN;
    int E = in_sizes[1] / 2;

    float* ws    = (float*)d_ws;
    float* hbuf  = ws + WS_H;
    float* kbuf  = hbuf + (size_t)N * HD;
    float* qbuf  = kbuf + (size_t)N * HD;
    float* vwbuf = qbuf + (size_t)N * HD;
    float* score = (float*)d_out;

    gnn_prep<<<6, 256, 0, stream>>>(W1, W2, Wk, Wq, Wv, Wsm, Wsc, bgat, bsc, ws);
    gnn_mlp<<<512, 256, 0, stream>>>(x, b1, b2, ws, hbuf, N);
    gnn_kqv<<<512, 256, 0, stream>>>(ws, bk, bq, bv, Wsc, kbuf, qbuf, vwbuf, score, N);
    gnn_edge<<<(E * 16 + 255) / 256, 256, 0, stream>>>(ei, kbuf, qbuf, vwbuf, score, E);
}